// Round 1
// baseline (206.605 us; speedup 1.0000x reference)
//
#include <hip/hip_runtime.h>

// Problem constants (from reference)
constexpr int BATCH = 1024;
constexpr int H     = 128;
constexpr int Wd    = 128;
constexpr int WPAD  = 132;   // HP = WP = 132 (pad 2)
constexpr int KH    = 10;
constexpr int KW    = 10;
constexpr int STR   = 5;
constexpr int NKH   = 25;
constexpr int NKW   = 25;
constexpr int NK    = NKH * NKW;      // 625
constexpr int KSZ   = KH * KW;        // 100
constexpr int SLAB  = NKW * KSZ;      // 2500 floats per ki

// Gather the 100 structured nonzeros of each W column into contiguous wg[k][di*10+dj].
__global__ void gather_weights(const float* __restrict__ W, float* __restrict__ wg) {
    int t = blockIdx.x * blockDim.x + threadIdx.x;
    if (t >= NK * KSZ) return;
    int k  = t / KSZ, i = t % KSZ;
    int di = i / KW,  dj = i % KW;
    int ki = k / NKW, kj = k % NKW;
    int row = (ki * STR + di) * WPAD + (kj * STR + dj);   // padded-row index
    wg[t] = W[row * NK + k];
}

// One block per image. Rolling 10-row LDS buffer, per-ki weight slab in LDS.
template <bool USE_WG>
__global__ __launch_bounds__(256)
void lc2d_kernel(const float* __restrict__ x,
                 const float* __restrict__ wg,
                 const float* __restrict__ Wfull,
                 const float* __restrict__ bias,
                 float* __restrict__ out) {
    __shared__ float xs[10][WPAD];   // 10 row slots, padded width; slot = (r+2)%10
    __shared__ float ws_s[SLAB];     // weights for current ki: [kj][di*10+dj]
    __shared__ float part[256];      // partial sums (250 used)

    const int b   = blockIdx.x;
    const int tid = threadIdx.x;
    const float* xb = x + (long)b * (H * Wd);

    // Initial fill: unpadded rows -2..7 -> slots 0..9 (slot = r+2)
    for (int idx = tid; idx < 10 * WPAD; idx += 256) {
        int slot = idx / WPAD, c = idx % WPAD;
        int r = slot - 2, cp = c - 2;
        float v = 0.f;
        if (r >= 0 && cp >= 0 && cp < Wd) v = xb[r * Wd + cp];
        xs[slot][c] = v;
    }
    // Weight slab for ki = 0
    if (USE_WG) {
        for (int idx = tid; idx < SLAB; idx += 256) ws_s[idx] = wg[idx];
    } else {
        for (int idx = tid; idx < SLAB; idx += 256) {
            int kj = idx / KSZ, i = idx % KSZ;
            int di = i / KW, dj = i % KW;
            int row = (0 * STR + di) * WPAD + (kj * STR + dj);
            ws_s[idx] = Wfull[row * NK + (0 * NKW + kj)];
        }
    }
    __syncthreads();

    for (int ki = 0; ki < NKH; ++ki) {
        // ---- compute phase: thread (kj, di) does the dj dot ----
        const int kj = tid / KH;
        const int di = tid % KH;
        if (tid < NKW * KH) {                      // 250 active
            const int slot = (ki * STR + di) % 10; // (r+2)%10 with r = ki*5+di-2
            const int base = kj * STR;             // padded column start
            const float* wr = &ws_s[kj * KSZ + di * KW];
            float sum = 0.f;
#pragma unroll
            for (int dj = 0; dj < KW; ++dj)
                sum += xs[slot][base + dj] * wr[dj];
            part[tid] = sum;
        }
        __syncthreads();

        // ---- phase 2: reduce+store (tid<25) concurrently with next-tile loads ----
        if (tid < NKW) {
            float s = 0.f;
#pragma unroll
            for (int j = 0; j < KH; ++j) s += part[tid * KH + j];
            out[(long)b * NK + ki * NKW + tid] = s + bias[ki * NKW + tid];
        }
        if (ki < NKH - 1) {
            // 5 new unpadded rows: ki*5+8 .. ki*5+12 overwrite the 5 dropped slots
            for (int idx = tid; idx < 5 * WPAD; idx += 256) {
                int q = idx / WPAD, c = idx % WPAD;
                int rr = ki * STR + 8 + q;
                int cp = c - 2;
                float v = 0.f;
                if (rr < H && cp >= 0 && cp < Wd) v = xb[rr * Wd + cp];
                xs[(rr + 2) % 10][c] = v;
            }
            // next weight slab
            if (USE_WG) {
                for (int idx = tid; idx < SLAB; idx += 256)
                    ws_s[idx] = wg[(ki + 1) * SLAB + idx];
            } else {
                for (int idx = tid; idx < SLAB; idx += 256) {
                    int kj2 = idx / KSZ, i = idx % KSZ;
                    int di2 = i / KW, dj2 = i % KW;
                    int row = ((ki + 1) * STR + di2) * WPAD + (kj2 * STR + dj2);
                    ws_s[idx] = Wfull[row * NK + ((ki + 1) * NKW + kj2)];
                }
            }
        }
        __syncthreads();
    }
}

extern "C" void kernel_launch(void* const* d_in, const int* in_sizes, int n_in,
                              void* d_out, int out_size, void* d_ws, size_t ws_size,
                              hipStream_t stream) {
    const float* x    = (const float*)d_in[0];
    const float* W    = (const float*)d_in[1];
    const float* bias = (const float*)d_in[2];
    float* out = (float*)d_out;

    if (ws_size >= (size_t)NK * KSZ * sizeof(float)) {
        float* wg = (float*)d_ws;
        gather_weights<<<(NK * KSZ + 255) / 256, 256, 0, stream>>>(W, wg);
        lc2d_kernel<true><<<BATCH, 256, 0, stream>>>(x, wg, W, bias, out);
    } else {
        lc2d_kernel<false><<<BATCH, 256, 0, stream>>>(x, nullptr, W, bias, out);
    }
}

// Round 2
// 132.495 us; speedup vs baseline: 1.5593x; 1.5593x over previous
//
#include <hip/hip_runtime.h>

// Problem constants (from reference)
constexpr int BATCH = 1024;
constexpr int H     = 128;
constexpr int Wd    = 128;
constexpr int WPAD  = 132;   // padded width (pad 2 each side)
constexpr int KH    = 10;
constexpr int KW    = 10;
constexpr int STR   = 5;
constexpr int NKH   = 25;
constexpr int NKW   = 25;
constexpr int NK    = NKH * NKW;   // 625
constexpr int KSZ   = KH * KW;     // 100

constexpr int IMGS  = 2;                 // images per inner iteration
constexpr int ITERS = 4;                 // iterations per block
constexpr int IPB   = IMGS * ITERS;      // 8 images per block
constexpr int GGRP  = BATCH / IPB;       // 128 image groups
// grid = NKH * GGRP = 3200 blocks, ~12 blocks/CU

// Gather the 100 structured nonzeros of each W column into contiguous wg[k][di*10+dj].
__global__ void gather_weights(const float* __restrict__ W, float* __restrict__ wg) {
    int t = blockIdx.x * blockDim.x + threadIdx.x;
    if (t >= NK * KSZ) return;
    int k  = t / KSZ, i = t % KSZ;
    int di = i / KW,  dj = i % KW;
    int ki = k / NKW, kj = k % NKW;
    int row = (ki * STR + di) * WPAD + (kj * STR + dj);   // padded-row index
    wg[t] = W[row * NK + k];
}

// Block = (ki, image-group). Thread (kj,di) holds its 10 weights in registers
// for the whole block. Per iteration: stage 2 images' 10-row bands (float4,
// coalesced), 10 MACs/thread, LDS reduce over di, fused bias, store.
template <bool USE_WG>
__global__ __launch_bounds__(256)
void lc2d_kernel(const float* __restrict__ x,
                 const float* __restrict__ wg,
                 const float* __restrict__ Wfull,
                 const float* __restrict__ bias,
                 float* __restrict__ out) {
    __shared__ float xs[IMGS][KH][WPAD];      // 2 x 10 x 132 floats = 10.3 KB
    __shared__ float part[IMGS][NKW * KH + 2]; // partials, 252 stride

    const int ki  = blockIdx.x % NKH;   // consecutive blocks share image rows -> L2 locality
    const int g   = blockIdx.x / NKH;
    const int tid = threadIdx.x;
    const int kj  = tid / KH;           // valid for tid < 250
    const int di  = tid % KH;

    // ---- one-time: weights into registers ----
    float wr[KW];
    if (tid < NKW * KH) {
        const int k = ki * NKW + kj;
        if (USE_WG) {
#pragma unroll
            for (int dj = 0; dj < KW; ++dj)
                wr[dj] = wg[k * KSZ + di * KW + dj];
        } else {
#pragma unroll
            for (int dj = 0; dj < KW; ++dj) {
                int row = (ki * STR + di) * WPAD + (kj * STR + dj);
                wr[dj] = Wfull[row * NK + k];
            }
        }
    }
    float bia = 0.f;
    if (tid < IMGS * NKW) bia = bias[ki * NKW + tid % NKW];

    // ---- one-time: zero the 4 pad columns (stage loop never touches them) ----
    if (tid < IMGS * KH * 4) {
        const int img = tid / (KH * 4);
        const int j   = tid % (KH * 4);
        const int r   = j / 4, c = j % 4;
        xs[img][r][(c < 2) ? c : (128 + c)] = 0.f;   // cols 0,1,130,131
    }

    const int r0 = ki * STR - 2;   // global (unpadded) row of band row 0

    for (int it = 0; it < ITERS; ++it) {
        const int b0 = g * IPB + it * IMGS;

        // ---- stage: 2 images x 10 rows x 32 float4, coalesced ----
        for (int i = tid; i < IMGS * KH * 32; i += 256) {
            const int img = i / (KH * 32);
            const int j   = i % (KH * 32);
            const int r   = j / 32, c4 = j % 32;
            const int rg  = r0 + r;
            float4 v = make_float4(0.f, 0.f, 0.f, 0.f);
            if (rg >= 0 && rg < H)
                v = reinterpret_cast<const float4*>(
                        x + (long)(b0 + img) * (H * Wd) + rg * Wd)[c4];
            float* dst = &xs[img][r][2 + c4 * 4];
            dst[0] = v.x; dst[1] = v.y; dst[2] = v.z; dst[3] = v.w;
        }
        __syncthreads();

        // ---- compute: 10 MACs per image, weights from registers ----
        if (tid < NKW * KH) {
#pragma unroll
            for (int img = 0; img < IMGS; ++img) {
                float s = 0.f;
                const float* xr = &xs[img][di][kj * STR];
#pragma unroll
                for (int dj = 0; dj < KW; ++dj)
                    s += xr[dj] * wr[dj];
                part[img][tid] = s;
            }
        }
        __syncthreads();

        // ---- reduce over di + bias + store (overlaps next stage) ----
        if (tid < IMGS * NKW) {
            const int img = tid / NKW, kj2 = tid % NKW;
            float s = 0.f;
#pragma unroll
            for (int j2 = 0; j2 < KH; ++j2)
                s += part[img][kj2 * KH + j2];
            out[(long)(b0 + img) * NK + ki * NKW + kj2] = s + bia;
        }
        // next iteration's first __syncthreads protects `part` (reduce done
        // before compute rewrites it) and `xs` (compute done before restage).
    }
}

extern "C" void kernel_launch(void* const* d_in, const int* in_sizes, int n_in,
                              void* d_out, int out_size, void* d_ws, size_t ws_size,
                              hipStream_t stream) {
    const float* x    = (const float*)d_in[0];
    const float* W    = (const float*)d_in[1];
    const float* bias = (const float*)d_in[2];
    float* out = (float*)d_out;

    const dim3 grid(NKH * GGRP);
    if (ws_size >= (size_t)NK * KSZ * sizeof(float)) {
        float* wg = (float*)d_ws;
        gather_weights<<<(NK * KSZ + 255) / 256, 256, 0, stream>>>(W, wg);
        lc2d_kernel<true><<<grid, 256, 0, stream>>>(x, wg, W, bias, out);
    } else {
        lc2d_kernel<false><<<grid, 256, 0, stream>>>(x, nullptr, W, bias, out);
    }
}